// Round 6
// baseline (239.249 us; speedup 1.0000x reference)
//
#include <hip/hip_runtime.h>

#define LQ 1024
#define DM 1024

// Split-bf16: x = hi + lo (both bf16); GEMMs run 3 MFMA passes (hh+hl+lh)
// for ~2^-17 relative precision (scores reach ~±100; softmax needs abs
// score error << 1e-1).

typedef __attribute__((ext_vector_type(8))) short bf16x8;
typedef __attribute__((ext_vector_type(4))) float f32x4;

#define MFMA(a, b, c) __builtin_amdgcn_mfma_f32_16x16x32_bf16((a), (b), (c), 0, 0, 0)
#define WAIT_LDS() __builtin_amdgcn_s_waitcnt(0xC07F)   // lgkmcnt(0) only

__device__ __forceinline__ unsigned short f2bf(float x) {
    unsigned int u = __float_as_uint(x);
    return (unsigned short)((u + 0x7FFFu + ((u >> 16) & 1u)) >> 16);
}
__device__ __forceinline__ float bf2f(unsigned short h) {
    return __uint_as_float(((unsigned int)h) << 16);
}
__device__ __forceinline__ void gload16(const void* gp, void* lp) {
    __builtin_amdgcn_global_load_lds(
        (const __attribute__((address_space(1))) void*)gp,
        (__attribute__((address_space(3))) void*)lp, 16, 0, 0);
}
__device__ __forceinline__ void store_split4(unsigned short* ph, unsigned short* pl,
                                             float4 v) {
    unsigned short h0 = f2bf(v.x), h1 = f2bf(v.y), h2 = f2bf(v.z), h3 = f2bf(v.w);
    uint2 a;
    a.x = (unsigned)h0 | ((unsigned)h1 << 16);
    a.y = (unsigned)h2 | ((unsigned)h3 << 16);
    *(uint2*)ph = a;
    unsigned short l0 = f2bf(v.x - bf2f(h0)), l1 = f2bf(v.y - bf2f(h1));
    unsigned short l2 = f2bf(v.z - bf2f(h2)), l3 = f2bf(v.w - bf2f(h3));
    uint2 b;
    b.x = (unsigned)l0 | ((unsigned)l1 << 16);
    b.y = (unsigned)l2 | ((unsigned)l3 << 16);
    *(uint2*)pl = b;
}

// ==================== merged prep: RMSNorm + 4 weight splits ===============
__device__ __forceinline__ void rms_body(
    int row, const float* __restrict__ x, const float* __restrict__ pt,
    const float* __restrict__ gq, const float* __restrict__ gkv,
    const float* __restrict__ gc,
    unsigned short* xqn_h, unsigned short* xqn_l,
    unsigned short* xkvn_h, unsigned short* xkvn_l,
    unsigned short* ptn_h, unsigned short* ptn_l)
{
    const int t = threadIdx.x;
    const bool isx = row < LQ;
    const float* src = isx ? (x + (size_t)row * DM)
                           : (pt + (size_t)(row - LQ) * DM);
    float4 v = ((const float4*)src)[t];
    float ss = v.x*v.x + v.y*v.y + v.z*v.z + v.w*v.w;
    #pragma unroll
    for (int o = 32; o > 0; o >>= 1) ss += __shfl_down(ss, o);
    __shared__ float red[4];
    if ((t & 63) == 0) red[t >> 6] = ss;
    __syncthreads();
    const float r = rsqrtf((red[0] + red[1] + red[2] + red[3]) * (1.0f / DM)
                           + 1.1920929e-07f);
    const size_t base = (size_t)(isx ? row : row - LQ) * DM + t * 4;
    if (isx) {
        float4 g1 = ((const float4*)gq)[t];
        float4 g2 = ((const float4*)gkv)[t];
        float4 y1, y2;
        y1.x = v.x*r*g1.x; y1.y = v.y*r*g1.y; y1.z = v.z*r*g1.z; y1.w = v.w*r*g1.w;
        y2.x = v.x*r*g2.x; y2.y = v.y*r*g2.y; y2.z = v.z*r*g2.z; y2.w = v.w*r*g2.w;
        store_split4(xqn_h + base, xqn_l + base, y1);
        store_split4(xkvn_h + base, xkvn_l + base, y2);
    } else {
        float4 g = ((const float4*)gc)[t];
        float4 y;
        y.x = v.x*r*g.x; y.y = v.y*r*g.y; y.z = v.z*r*g.z; y.w = v.w*r*g.w;
        store_split4(ptn_h + base, ptn_l + base, y);
    }
}

__device__ __forceinline__ void wsplit_body(
    const float* __restrict__ in, unsigned short* oh, unsigned short* ol,
    int K, int N, int bx, int by)
{
    __shared__ float T[64 * 65];
    const int t = threadIdx.x;
    const int tx = t & 15, ty = t >> 4;
    const int c0 = bx * 64, r0 = by * 64;
    #pragma unroll
    for (int p = 0; p < 4; ++p) {
        int row = ty + p * 16;
        float4 v = *(const float4*)(in + (size_t)(r0 + row) * N + c0 + tx * 4);
        T[row * 65 + tx * 4 + 0] = v.x;
        T[row * 65 + tx * 4 + 1] = v.y;
        T[row * 65 + tx * 4 + 2] = v.z;
        T[row * 65 + tx * 4 + 3] = v.w;
    }
    __syncthreads();
    #pragma unroll
    for (int p = 0; p < 4; ++p) {
        int n = ty + p * 16;
        float4 w;
        w.x = T[(tx * 4 + 0) * 65 + n];
        w.y = T[(tx * 4 + 1) * 65 + n];
        w.z = T[(tx * 4 + 2) * 65 + n];
        w.w = T[(tx * 4 + 3) * 65 + n];
        size_t o = (size_t)(c0 + n) * K + r0 + tx * 4;
        store_split4(oh + o, ol + o, w);
    }
}

__global__ __launch_bounds__(256) void prep_kernel(
    const float* __restrict__ x, const float* __restrict__ pt,
    const float* __restrict__ gq, const float* __restrict__ gkv,
    const float* __restrict__ gc,
    const float* __restrict__ Wq, const float* __restrict__ Wkv,
    const float* __restrict__ Wc, const float* __restrict__ Wout,
    unsigned short* xqn_h, unsigned short* xqn_l,
    unsigned short* xkvn_h, unsigned short* xkvn_l,
    unsigned short* ptn_h, unsigned short* ptn_l,
    unsigned short* WqT_h, unsigned short* WqT_l,
    unsigned short* WkvT_h, unsigned short* WkvT_l,
    unsigned short* WcT_h, unsigned short* WcT_l,
    unsigned short* WoT_h, unsigned short* WoT_l)
{
    const int b = blockIdx.x;
    if (b < 2048) {
        rms_body(b, x, pt, gq, gkv, gc, xqn_h, xqn_l, xkvn_h, xkvn_l, ptn_h, ptn_l);
    } else if (b < 2304) {
        int s = b - 2048; wsplit_body(Wq, WqT_h, WqT_l, 1024, 1024, s & 15, s >> 4);
    } else if (b < 2816) {
        int s = b - 2304; wsplit_body(Wkv, WkvT_h, WkvT_l, 1024, 2048, s & 31, s >> 5);
    } else if (b < 3072) {
        int s = b - 2816; wsplit_body(Wc, WcT_h, WcT_l, 1024, 1024, s & 15, s >> 4);
    } else {
        int s = b - 3072; wsplit_body(Wout, WoT_h, WoT_l, 1024, 1024, s & 15, s >> 4);
    }
}

// ====== split-bf16 MFMA GEMM: 128x64 tile, 256 thr (4 waves, 2x2) ==========
// A: [1024][1024] bf16 row-major; B: [N][1024] (W^T). BK=32 (2-way banks).
__device__ __forceinline__ void gemm3p(
    const unsigned short* __restrict__ Ah, const unsigned short* __restrict__ Al,
    const unsigned short* __restrict__ Bh, const unsigned short* __restrict__ Bl,
    const float* __restrict__ bias, float* __restrict__ out, int N, int mt, int nt)
{
    __shared__ unsigned short sAh[128 * 32], sAl[128 * 32];
    __shared__ unsigned short sBh[64 * 32], sBl[64 * 32];
    const int t = threadIdx.x;
    const int lane = t & 63, w = t >> 6;
    const int wm = w >> 1, wn = w & 1;          // 2x2 wave grid; wave = 64x32
    const int n16 = lane & 15, quad = lane >> 4;
    const int srow = t >> 2, scol = (t & 3) * 8;
    f32x4 zero = {0.f, 0.f, 0.f, 0.f};
    f32x4 acc[4][2];
    #pragma unroll
    for (int ms = 0; ms < 4; ++ms)
        #pragma unroll
        for (int ns = 0; ns < 2; ++ns) acc[ms][ns] = zero;

    for (int kt = 0; kt < 32; ++kt) {
        const int k0 = kt * 32;
        __syncthreads();
        #pragma unroll
        for (int p = 0; p < 2; ++p) {   // A: 128 rows = 2 x 64-row calls
            const size_t ga = (size_t)(mt * 128 + srow + p * 64) * 1024 + k0 + scol;
            const int lb = w * 512 + p * 2048;
            gload16(Ah + ga, sAh + lb);
            gload16(Al + ga, sAl + lb);
        }
        {   // B: 64 rows = 1 call
            const size_t gb = (size_t)(nt * 64 + srow) * 1024 + k0 + scol;
            gload16(Bh + gb, sBh + w * 512);
            gload16(Bl + gb, sBl + w * 512);
        }
        __syncthreads();
        bf16x8 afh[4], afl[4], bfh[2], bfl[2];
        #pragma unroll
        for (int ms = 0; ms < 4; ++ms) {
            int r = wm * 64 + ms * 16 + n16;
            afh[ms] = *(const bf16x8*)&sAh[r * 32 + quad * 8];
            afl[ms] = *(const bf16x8*)&sAl[r * 32 + quad * 8];
        }
        #pragma unroll
        for (int ns = 0; ns < 2; ++ns) {
            int r = wn * 32 + ns * 16 + n16;
            bfh[ns] = *(const bf16x8*)&sBh[r * 32 + quad * 8];
            bfl[ns] = *(const bf16x8*)&sBl[r * 32 + quad * 8];
        }
        #pragma unroll
        for (int ms = 0; ms < 4; ++ms)
            #pragma unroll
            for (int ns = 0; ns < 2; ++ns) {
                acc[ms][ns] = MFMA(afh[ms], bfh[ns], acc[ms][ns]);
                acc[ms][ns] = MFMA(afh[ms], bfl[ns], acc[ms][ns]);
                acc[ms][ns] = MFMA(afl[ms], bfh[ns], acc[ms][ns]);
            }
    }
    #pragma unroll
    for (int ns = 0; ns < 2; ++ns) {
        const int col = nt * 64 + wn * 32 + ns * 16 + n16;
        const float bv = bias[col];
        #pragma unroll
        for (int ms = 0; ms < 4; ++ms) {
            const int row0 = mt * 128 + wm * 64 + ms * 16 + quad * 4;
            #pragma unroll
            for (int reg = 0; reg < 4; ++reg)
                out[(size_t)(row0 + reg) * N + col] = acc[ms][ns][reg] + bv;
        }
    }
}

// Q(128) | KV(256) | C(128)  -> 512 blocks, 2 blocks/CU
__global__ __launch_bounds__(256) void proj_kernel(
    const unsigned short* __restrict__ xqn_h, const unsigned short* __restrict__ xqn_l,
    const unsigned short* __restrict__ xkvn_h, const unsigned short* __restrict__ xkvn_l,
    const unsigned short* __restrict__ ptn_h, const unsigned short* __restrict__ ptn_l,
    const unsigned short* __restrict__ WqT_h, const unsigned short* __restrict__ WqT_l,
    const unsigned short* __restrict__ WkvT_h, const unsigned short* __restrict__ WkvT_l,
    const unsigned short* __restrict__ WcT_h, const unsigned short* __restrict__ WcT_l,
    const float* __restrict__ bq, const float* __restrict__ bkv,
    const float* __restrict__ bc,
    float* __restrict__ Qb, float* __restrict__ KVb, float* __restrict__ Cb)
{
    const int bid = blockIdx.x;
    if (bid < 128) {
        gemm3p(xqn_h, xqn_l, WqT_h, WqT_l, bq, Qb, 1024, bid >> 4, bid & 15);
    } else if (bid < 384) {
        int b2 = bid - 128;
        gemm3p(xkvn_h, xkvn_l, WkvT_h, WkvT_l, bkv, KVb, 2048, b2 >> 5, b2 & 31);
    } else {
        int b2 = bid - 384;
        gemm3p(ptn_h, ptn_l, WcT_h, WcT_l, bc, Cb, 1024, b2 >> 4, b2 & 15);
    }
}

// ================== prefix sums of C over rows =============================
__global__ __launch_bounds__(256) void csum_kernel(const float* __restrict__ Cb,
                                                   float* __restrict__ csum)
{
    const int cid = blockIdx.x >> 2;
    const int col = ((blockIdx.x & 3) << 8) + threadIdx.x;
    const float* p = Cb + (size_t)cid * 32 * 1024 + col;
    float s = 0.f;
    #pragma unroll 8
    for (int r = 0; r < 32; ++r) s += p[(size_t)r * 1024];
    csum[cid * 1024 + col] = s;
}

__global__ __launch_bounds__(256) void scanp_kernel(const float* __restrict__ Cb,
                                                    const float* __restrict__ csum,
                                                    float* __restrict__ Pb)
{
    const int cid = blockIdx.x >> 2;
    const int col = ((blockIdx.x & 3) << 8) + threadIdx.x;
    float run = 0.f;
    for (int c = 0; c < cid; ++c) run += csum[c * 1024 + col];
    const float* p = Cb + (size_t)cid * 32 * 1024 + col;
    float* q = Pb + (size_t)cid * 32 * 1024 + col;
    for (int r = 0; r < 32; ++r) {
        q[(size_t)r * 1024] = run;
        run += p[(size_t)r * 1024];
    }
    if (cid == 31) Pb[(size_t)1024 * 1024 + col] = run;
}

// ==== merged: A/B build (split bf16) + V transpose to bf16 [h][d][j] =======
__global__ __launch_bounds__(256) void abv_kernel(
    const float* __restrict__ Qb, const float* __restrict__ KVb,
    const float* __restrict__ Pb, const int* __restrict__ cwp,
    unsigned short* __restrict__ Aah, unsigned short* __restrict__ Aal,
    unsigned short* __restrict__ Bah, unsigned short* __restrict__ Bal,
    unsigned short* __restrict__ VT)
{
    const int b = blockIdx.x;
    if (b < 4096) {
        const int gid = b * 256 + threadIdx.x;
        const int i = gid >> 10;
        const int col = gid & 1023;
        const int h = col >> 6, dd = col & 63;
        const int cw = *cwp;
        const int E = min(i + cw, LQ);
        const int S = max(i - cw, 0);
        const float pe = Pb[(size_t)E * 1024 + col];
        const float ps = Pb[(size_t)S * 1024 + col];
        const float q = Qb[gid];
        const float k = KVb[(size_t)i * 2048 + col];
        const float scale = 0.125f;   // 64^-0.5
        const size_t base = ((size_t)(h * 1024 + i)) * 128;
        float a0 = q, a1 = q * pe;
        float b0 = k * (scale - ps), b1 = k;
        unsigned short hv;
        hv = f2bf(a0); Aah[base + dd] = hv;      Aal[base + dd] = f2bf(a0 - bf2f(hv));
        hv = f2bf(a1); Aah[base + 64 + dd] = hv; Aal[base + 64 + dd] = f2bf(a1 - bf2f(hv));
        hv = f2bf(b0); Bah[base + dd] = hv;      Bal[base + dd] = f2bf(b0 - bf2f(hv));
        hv = f2bf(b1); Bah[base + 64 + dd] = hv; Bal[base + 64 + dd] = f2bf(b1 - bf2f(hv));
    } else {
        const int s = b - 4096;
        const int h = s >> 4, j0 = (s & 15) * 64;
        __shared__ float T[64 * 65];
        const int t = threadIdx.x;
        const int tx = t & 15, ty = t >> 4;
        #pragma unroll
        for (int p = 0; p < 4; ++p) {
            int j = ty + p * 16;
            float4 v = *(const float4*)(KVb + (size_t)(j0 + j) * 2048 + 1024 + h * 64 + tx * 4);
            T[j * 65 + tx * 4 + 0] = v.x;
            T[j * 65 + tx * 4 + 1] = v.y;
            T[j * 65 + tx * 4 + 2] = v.z;
            T[j * 65 + tx * 4 + 3] = v.w;
        }
        __syncthreads();
        #pragma unroll
        for (int p = 0; p < 4; ++p) {
            int d = ty + p * 16;
            unsigned short e0 = f2bf(T[(tx * 4 + 0) * 65 + d]);
            unsigned short e1 = f2bf(T[(tx * 4 + 1) * 65 + d]);
            unsigned short e2 = f2bf(T[(tx * 4 + 2) * 65 + d]);
            unsigned short e3 = f2bf(T[(tx * 4 + 3) * 65 + d]);
            uint2 pk;
            pk.x = (unsigned)e0 | ((unsigned)e1 << 16);
            pk.y = (unsigned)e2 | ((unsigned)e3 << 16);
            *(uint2*)(VT + (size_t)(h * 64 + d) * 1024 + j0 + tx * 4) = pk;
        }
    }
}

// ============ flash attention: block = (head, 32-row i-tile) ===============
// 512 blocks x 8 waves (512 thr; 2 blocks/CU -> 16 waves/CU, 4/SIMD).
// Wave w = (j-phase = w>>1, i-sub = w&1): the two i-sub waves of a phase
// read the SAME B fragments (CU-local reuse -> halves external traffic vs
// 16-row blocks). j-phases round-robin j-tiles; 8 partials combined in LDS.
// Per-CU balance: blocks {q, 31-q} give sum(njt) = 17 constant; b&15 = h
// keeps head->XCD affinity for L2 locality.
__global__ __launch_bounds__(512, 4) void attn_kernel(
    const unsigned short* __restrict__ Aah, const unsigned short* __restrict__ Aal,
    const unsigned short* __restrict__ Bah, const unsigned short* __restrict__ Bal,
    const unsigned short* __restrict__ VT,
    unsigned short* __restrict__ wvh, unsigned short* __restrict__ wvl)
{
    __shared__ unsigned short PsAll[8][16 * 68];   // per-wave P scratch (17 KB)
    __shared__ float cO[8][16 * 68];               // partial O (35 KB)
    __shared__ float cM[8][16], cL[8][16];

    const int t = threadIdx.x;
    const int lane = t & 63, wid = t >> 6;
    const int jp = wid >> 1, isub = wid & 1;
    unsigned short* Ps = PsAll[wid];
    const int b = blockIdx.x;
    const int h = b & 15;
    const int q4 = (b >> 4) & 15;
    const int it32 = (b >> 8) ? (31 - q4) : q4;
    const int i0b = it32 * 32;
    const int i0 = i0b + isub * 16;
    const int njt = (it32 >> 1) + 1;
    const int n16 = lane & 15, quad = lane >> 4;

    // A fragments direct from global (row n16, k chunk kc*32 + quad*8)
    bf16x8 afh[4], afl[4];
    {
        const size_t ar = ((size_t)(h * 1024 + i0 + n16)) * 128 + quad * 8;
        #pragma unroll
        for (int kc = 0; kc < 4; ++kc) {
            afh[kc] = *(const bf16x8*)(Aah + ar + kc * 32);
            afl[kc] = *(const bf16x8*)(Aal + ar + kc * 32);
        }
    }

    f32x4 zero = {0.f, 0.f, 0.f, 0.f};
    f32x4 oacc[4];
    #pragma unroll
    for (int dt = 0; dt < 4; ++dt) oacc[dt] = zero;
    float mrow[4], lrow[4];
    #pragma unroll
    for (int reg = 0; reg < 4; ++reg) { mrow[reg] = -1e30f; lrow[reg] = 0.f; }

    for (int jt = jp; jt < njt; jt += 4) {
        const int j0 = jt * 64;
        // S = A*B^T : B fragments direct from global
        f32x4 s[4];
        #pragma unroll
        for (int jj = 0; jj < 4; ++jj) s[jj] = zero;
        #pragma unroll
        for (int jj = 0; jj < 4; ++jj) {
            const size_t br = ((size_t)(h * 1024 + j0 + jj * 16 + n16)) * 128 + quad * 8;
            #pragma unroll
            for (int kc = 0; kc < 4; ++kc) {
                bf16x8 bh = *(const bf16x8*)(Bah + br + kc * 32);
                bf16x8 bl = *(const bf16x8*)(Bal + br + kc * 32);
                s[jj] = MFMA(afh[kc], bh, s[jj]);
                s[jj] = MFMA(afh[kc], bl, s[jj]);
                s[jj] = MFMA(afl[kc], bh, s[jj]);
            }
        }

        // prefetch V fragments (independent of softmax) to overlap latency
        bf16x8 vf[4][2];
        #pragma unroll
        for (int dt = 0; dt < 4; ++dt) {
            const size_t vr = ((size_t)(h * 64 + dt * 16 + n16)) * 1024 + j0 + quad * 8;
            vf[dt][0] = *(const bf16x8*)(VT + vr);
            vf[dt][1] = *(const bf16x8*)(VT + vr + 32);
        }

        if (jt == njt - 1) {   // diagonal tile: causal mask
            const int ibase = i0 + quad * 4;
            #pragma unroll
            for (int jj = 0; jj < 4; ++jj) {
                const int j = j0 + jj * 16 + n16;
                #pragma unroll
                for (int reg = 0; reg < 4; ++reg)
                    if (j > ibase + reg) s[jj][reg] = -1e30f;
            }
        }

        // online softmax (row = quad*4+reg; reduce across n16 lanes)
        float alpha[4];
        #pragma unroll
        for (int reg = 0; reg < 4; ++reg) {
            float mt_ = fmaxf(fmaxf(s[0][reg], s[1][reg]), fmaxf(s[2][reg], s[3][reg]));
            mt_ = fmaxf(mt_, __shfl_xor(mt_, 1));
            mt_ = fmaxf(mt_, __shfl_xor(mt_, 2));
            mt_ = fmaxf(mt_, __shfl_xor(mt_, 4));
            mt_ = fmaxf(mt_, __shfl_xor(mt_, 8));
            const float mn = fmaxf(mrow[reg], mt_);
            alpha[reg] = __expf(mrow[reg] - mn);
            mrow[reg] = mn;
            float rs = 0.f;
            #pragma unroll
            for (int jj = 0; jj < 4; ++jj) {
                float p = __expf(s[jj][reg] - mn);
                s[jj][reg] = p;
                rs += p;
            }
            rs += __shfl_xor(rs, 1); rs += __shfl_xor(rs, 2);
            rs += __shfl_xor(rs, 4); rs += __shfl_xor(rs, 8);
            lrow[reg] = lrow[reg] * alpha[reg] + rs;
        }

        // P: C-layout -> A-operand layout via per-wave LDS (no barrier)
        WAIT_LDS();   // prior Ps reads retired
        #pragma unroll
        for (int jj = 0; jj < 4; ++jj)
            #pragma unroll
            for (int reg = 0; reg < 4; ++reg)
                Ps[(quad * 4 + reg) * 68 + jj * 16 + n16] = f2bf(s[jj][reg]);
        WAIT_LDS();   // writes visible in-wave
        bf16x8 pf0 = *(const bf16x8*)&Ps[n16 * 68 + quad * 8];
        bf16x8 pf1 = *(const bf16x8*)&Ps[n16 * 68 + 32 + quad * 8];

        // PV with prefetched V
        #pragma unroll
        for (int dt = 0; dt < 4; ++dt) {
            #pragma unroll
            for (int reg = 0; reg < 4; ++reg) oacc[dt][reg] *= alpha[reg];
            oacc[dt] = MFMA(pf0, vf[dt][0], oacc[dt]);
            oacc[dt] = MFMA(pf1, vf[dt][1], oacc[dt]);
        }
    }

    // ---- block-level combine of the 8 wave partials (4 per i-sub) ----
    #pragma unroll
    for (int dt = 0; dt < 4; ++dt)
        #pragma unroll
        for (int reg = 0; reg < 4; ++reg)
            cO[wid][(quad * 4 + reg) * 68 + dt * 16 + n16] = oacc[dt][reg];
    if (n16 == 0) {
        #pragma unroll
        for (int reg = 0; reg < 4; ++reg) {
            cM[wid][quad * 4 + reg] = mrow[reg];
            cL[wid][quad * 4 + reg] = lrow[reg];
        }
    }
    __syncthreads();
    #pragma unroll
    for (int u = 0; u < 4; ++u) {
        const int p = u * 512 + t;                 // 0..2047
        const int s = p >> 10;                     // i-sub
        const int rem = p & 1023;
        const int r = rem >> 6, d = rem & 63;
        const int w0 = s, w1 = s + 2, w2 = s + 4, w3 = s + 6;
        const float m0 = cM[w0][r], m1 = cM[w1][r], m2 = cM[w2][r], m3 = cM[w3][r];
        const float M = fmaxf(fmaxf(m0, m1), fmaxf(m2, m3));
        const float e0 = __expf(m0 - M), e1 = __expf(m1 - M);
        const float e2 = __expf(m2 - M), e3 = __expf(m3 - M);
        const float L = e0 * cL[w0][r] + e1 * cL[w1][r] + e2 * cL[w2][r] + e3 * cL[w3][r];
        const float o = e0 * cO[w0][r * 68 + d] + e1 * cO[w1][r * 68 + d]
                      + e2 * cO[w2][r * 68 + d] + e3 * cO[w3][r * 68 + d];
        const float v = o / L;
        const size_t oi = (size_t)(i0b + s * 16 + r) * 1024 + h * 64 + d;
        const unsigned short hv = f2bf(v);
        wvh[oi] = hv;
        wvl[oi] = f2bf(v - bf2f(hv));
    }
}

// ====== out GEMM: 64x32 tile, 128 thr (2 waves), 512 blocks ================
__global__ __launch_bounds__(128) void outgemm_kernel(
    const unsigned short* __restrict__ Ah, const unsigned short* __restrict__ Al,
    const unsigned short* __restrict__ Bh, const unsigned short* __restrict__ Bl,
    const float* __restrict__ bias, float* __restrict__ out)
{
    __shared__ unsigned short sAh[64 * 32], sAl[64 * 32];
    __shared__ unsigned short sBh[32 * 32], sBl[32 * 32];
    const int t = threadIdx.x;
    const int lane = t & 63, w = t >> 6;
    const int n16 = lane & 15, quad = lane >> 4;
    const int mt = blockIdx.x >> 5, nt = blockIdx.x & 31;
    const int srow = t >> 2, scol = (t & 3) * 8;
    f32x4 zero = {0.f, 0.f, 0.f, 0.f};
    f32x4 acc[2][2];
    #pragma unroll
    for (int ms = 0; ms < 2; ++ms)
        #pragma unroll
        for (int ns = 0; ns < 2; ++ns) acc[ms][ns] = zero;

    for (int kt = 0; kt < 32; ++kt) {
        const int k0 = kt * 32;
        __syncthreads();
        #pragma unroll
        for (int p = 0; p < 2; ++p) {   // A: 64 rows = 2 x 32-row calls
            const size_t ga = (size_t)(mt * 64 + srow + p * 32) * 1024 + k0 + scol;
            const int lb = w * 512 + p * 1024;
            gload16(Ah + ga, sAh + lb);
            gload16(Al + ga, sAl + lb);
        }
        {   // B: 32 rows = 1 call
            const size_t gb = (size_t)(nt * 32 + srow) * 1024 + k0 + scol;
            gload16(Bh + gb, sBh + w * 512);
            gload16(Bl + gb, sBl + w * 512);
        }
        __syncthreads();
        bf16x8 ah[2], al[2], bh[2], bl[2];
        #pragma unroll
        for (int ms = 0; ms < 2; ++ms) {
            int r = w * 32 + ms * 16 + n16;
            ah[ms] = *(const bf16x8*)&sAh[r * 32 + quad * 8];
            al[ms] = *(const bf16x8*)&sAl[r * 32 + quad * 8];
        }
        #pragma unroll
        for (int ns = 0; ns < 2; ++ns) {
            int r = ns * 16 + n16;
            bh[ns] = *(const bf16x8*)&sBh[r * 32 + quad * 8];
            bl[ns] = *(const bf16x8*)&sBl[r * 32 + quad * 8];
        }
        #pragma unroll
        for (int ms = 0; ms < 2; ++ms)
            #pragma unroll
            for (int ns = 0; ns < 2; ++ns) {
                acc[ms][ns] = MFMA(ah[ms], bh[ns], acc[ms][ns]);
                acc[ms][ns] = MFMA(ah[ms], bl[ns], acc[ms][ns]);
                acc[ms][ns] = MFMA(al[ms], bh[ns], acc[ms][ns]);
            }
    }
    #pragma unroll
    for (int ns = 0; ns < 2; ++ns) {
        const int col = nt * 32 + ns * 16 + n16;
        const float bv = bias[col];
        #pragma unroll
        for (int ms = 0; ms < 2; ++ms) {
            const int row0 = mt * 64 + w * 32 + ms * 16 + quad * 4;
            #pragma unroll
            for (int reg = 0; reg < 4; ++reg)
                out[(size_t)(row0 + reg) * 1024 + col] = acc[ms][ns][reg] + bv;
        }
    }
}

// ================================ launch ===================================
extern "C" void kernel_launch(void* const* d_in, const int* in_sizes, int n_in,
                              void* d_out, int out_size, void* d_ws, size_t ws_size,
                              hipStream_t stream) {
    (void)in_sizes; (void)n_in; (void)out_size; (void)ws_size;
    const float* x    = (const float*)d_in[0];
    const float* pt   = (const float*)d_in[1];
    const float* gq   = (const float*)d_in[3];
    const float* Wq   = (const float*)d_in[4];
    const float* bq   = (const float*)d_in[5];
    const float* gkv  = (const float*)d_in[6];
    const float* Wkv  = (const float*)d_in[7];
    const float* bkv  = (const float*)d_in[8];
    const float* gc   = (const float*)d_in[9];
    const float* Wc   = (const float*)d_in[10];
    const float* bc   = (const float*)d_in[11];
    const float* Wout = (const float*)d_in[12];
    const float* bout = (const float*)d_in[13];
    const int*   cw   = (const int*)d_in[14];
    float* out = (float*)d_out;

    char* W = (char*)d_ws;
    const size_t MB = 1u << 20;
    #define US(off) ((unsigned short*)(W + (size_t)(off)))
    #define FP(off) ((float*)(W + (size_t)(off)))
    // prep pool (dead after proj):
    unsigned short* xqn_h  = US(0 * MB);
    unsigned short* xqn_l  = US(2 * MB);
    unsigned short* xkvn_h = US(4 * MB);
    unsigned short* xkvn_l = US(6 * MB);
    unsigned short* ptn_h  = US(8 * MB);
    unsigned short* ptn_l  = US(10 * MB);
    unsigned short* WqT_h  = US(12 * MB);
    unsigned short* WqT_l  = US(14 * MB);
    unsigned short* WkvT_h = US(16 * MB);
    unsigned short* WkvT_l = US(20 * MB);
    unsigned short* WcT_h  = US(24 * MB);
    unsigned short* WcT_l  = US(26 * MB);
    unsigned short* WoT_h  = US(28 * MB);   // live till end
    unsigned short* WoT_l  = US(30 * MB);
    float* Qb   = FP(32 * MB);   // 4 MB
    float* KVb  = FP(36 * MB);   // 8 MB
    float* Cb   = FP(44 * MB);   // 4 MB
    float* Pb   = FP(48 * MB);   // 4.004 MB
    float* csum = FP(52 * MB + 256 * 1024);   // 128 KB
    // reuse of dead prep pool:
    unsigned short* Aah = US(0 * MB);    // 4 MB each
    unsigned short* Aal = US(4 * MB);
    unsigned short* Bah = US(8 * MB);
    unsigned short* Bal = US(12 * MB);
    unsigned short* VTb = US(16 * MB);   // 2 MB
    unsigned short* wv_h = US(18 * MB);  // 2 MB
    unsigned short* wv_l = US(20 * MB);  // 2 MB
    #undef US
    #undef FP

    hipLaunchKernelGGL(prep_kernel, dim3(3328), dim3(256), 0, stream,
                       x, pt, gq, gkv, gc, Wq, Wkv, Wc, Wout,
                       xqn_h, xqn_l, xkvn_h, xkvn_l, ptn_h, ptn_l,
                       WqT_h, WqT_l, WkvT_h, WkvT_l, WcT_h, WcT_l, WoT_h, WoT_l);
    hipLaunchKernelGGL(proj_kernel, dim3(512), dim3(256), 0, stream,
                       xqn_h, xqn_l, xkvn_h, xkvn_l, ptn_h, ptn_l,
                       WqT_h, WqT_l, WkvT_h, WkvT_l, WcT_h, WcT_l,
                       bq, bkv, bc, Qb, KVb, Cb);
    hipLaunchKernelGGL(csum_kernel, dim3(128), dim3(256), 0, stream, Cb, csum);
    hipLaunchKernelGGL(scanp_kernel, dim3(128), dim3(256), 0, stream, Cb, csum, Pb);
    hipLaunchKernelGGL(abv_kernel, dim3(4352), dim3(256), 0, stream,
                       Qb, KVb, Pb, cw, Aah, Aal, Bah, Bal, VTb);
    hipLaunchKernelGGL(attn_kernel, dim3(512), dim3(512), 0, stream,
                       Aah, Aal, Bah, Bal, VTb, wv_h, wv_l);
    hipLaunchKernelGGL(outgemm_kernel, dim3(512), dim3(128), 0, stream,
                       wv_h, wv_l, WoT_h, WoT_l, bout, out);
}

// Round 7
// 234.156 us; speedup vs baseline: 1.0217x; 1.0217x over previous
//
#include <hip/hip_runtime.h>

#define LQ 1024
#define DM 1024

// Split-bf16: x = hi + lo (both bf16); GEMMs run 3 MFMA passes (hh+hl+lh)
// for ~2^-17 relative precision (scores reach ~±100; softmax needs abs
// score error << 1e-1).

typedef __attribute__((ext_vector_type(8))) short bf16x8;
typedef __attribute__((ext_vector_type(4))) float f32x4;

#define MFMA(a, b, c) __builtin_amdgcn_mfma_f32_16x16x32_bf16((a), (b), (c), 0, 0, 0)
#define WAIT_LDS() __builtin_amdgcn_s_waitcnt(0xC07F)   // lgkmcnt(0) only

__device__ __forceinline__ unsigned short f2bf(float x) {
    unsigned int u = __float_as_uint(x);
    return (unsigned short)((u + 0x7FFFu + ((u >> 16) & 1u)) >> 16);
}
__device__ __forceinline__ float bf2f(unsigned short h) {
    return __uint_as_float(((unsigned int)h) << 16);
}
__device__ __forceinline__ void gload16(const void* gp, void* lp) {
    __builtin_amdgcn_global_load_lds(
        (const __attribute__((address_space(1))) void*)gp,
        (__attribute__((address_space(3))) void*)lp, 16, 0, 0);
}
__device__ __forceinline__ void store_split4(unsigned short* ph, unsigned short* pl,
                                             float4 v) {
    unsigned short h0 = f2bf(v.x), h1 = f2bf(v.y), h2 = f2bf(v.z), h3 = f2bf(v.w);
    uint2 a;
    a.x = (unsigned)h0 | ((unsigned)h1 << 16);
    a.y = (unsigned)h2 | ((unsigned)h3 << 16);
    *(uint2*)ph = a;
    unsigned short l0 = f2bf(v.x - bf2f(h0)), l1 = f2bf(v.y - bf2f(h1));
    unsigned short l2 = f2bf(v.z - bf2f(h2)), l3 = f2bf(v.w - bf2f(h3));
    uint2 b;
    b.x = (unsigned)l0 | ((unsigned)l1 << 16);
    b.y = (unsigned)l2 | ((unsigned)l3 << 16);
    *(uint2*)pl = b;
}

// ==================== merged prep: RMSNorm + 4 weight splits ===============
__device__ __forceinline__ void rms_body(
    int row, const float* __restrict__ x, const float* __restrict__ pt,
    const float* __restrict__ gq, const float* __restrict__ gkv,
    const float* __restrict__ gc,
    unsigned short* xqn_h, unsigned short* xqn_l,
    unsigned short* xkvn_h, unsigned short* xkvn_l,
    unsigned short* ptn_h, unsigned short* ptn_l)
{
    const int t = threadIdx.x;
    const bool isx = row < LQ;
    const float* src = isx ? (x + (size_t)row * DM)
                           : (pt + (size_t)(row - LQ) * DM);
    float4 v = ((const float4*)src)[t];
    float ss = v.x*v.x + v.y*v.y + v.z*v.z + v.w*v.w;
    #pragma unroll
    for (int o = 32; o > 0; o >>= 1) ss += __shfl_down(ss, o);
    __shared__ float red[4];
    if ((t & 63) == 0) red[t >> 6] = ss;
    __syncthreads();
    const float r = rsqrtf((red[0] + red[1] + red[2] + red[3]) * (1.0f / DM)
                           + 1.1920929e-07f);
    const size_t base = (size_t)(isx ? row : row - LQ) * DM + t * 4;
    if (isx) {
        float4 g1 = ((const float4*)gq)[t];
        float4 g2 = ((const float4*)gkv)[t];
        float4 y1, y2;
        y1.x = v.x*r*g1.x; y1.y = v.y*r*g1.y; y1.z = v.z*r*g1.z; y1.w = v.w*r*g1.w;
        y2.x = v.x*r*g2.x; y2.y = v.y*r*g2.y; y2.z = v.z*r*g2.z; y2.w = v.w*r*g2.w;
        store_split4(xqn_h + base, xqn_l + base, y1);
        store_split4(xkvn_h + base, xkvn_l + base, y2);
    } else {
        float4 g = ((const float4*)gc)[t];
        float4 y;
        y.x = v.x*r*g.x; y.y = v.y*r*g.y; y.z = v.z*r*g.z; y.w = v.w*r*g.w;
        store_split4(ptn_h + base, ptn_l + base, y);
    }
}

__device__ __forceinline__ void wsplit_body(
    const float* __restrict__ in, unsigned short* oh, unsigned short* ol,
    int K, int N, int bx, int by)
{
    __shared__ float T[64 * 65];
    const int t = threadIdx.x;
    const int tx = t & 15, ty = t >> 4;
    const int c0 = bx * 64, r0 = by * 64;
    #pragma unroll
    for (int p = 0; p < 4; ++p) {
        int row = ty + p * 16;
        float4 v = *(const float4*)(in + (size_t)(r0 + row) * N + c0 + tx * 4);
        T[row * 65 + tx * 4 + 0] = v.x;
        T[row * 65 + tx * 4 + 1] = v.y;
        T[row * 65 + tx * 4 + 2] = v.z;
        T[row * 65 + tx * 4 + 3] = v.w;
    }
    __syncthreads();
    #pragma unroll
    for (int p = 0; p < 4; ++p) {
        int n = ty + p * 16;
        float4 w;
        w.x = T[(tx * 4 + 0) * 65 + n];
        w.y = T[(tx * 4 + 1) * 65 + n];
        w.z = T[(tx * 4 + 2) * 65 + n];
        w.w = T[(tx * 4 + 3) * 65 + n];
        size_t o = (size_t)(c0 + n) * K + r0 + tx * 4;
        store_split4(oh + o, ol + o, w);
    }
}

__global__ __launch_bounds__(256) void prep_kernel(
    const float* __restrict__ x, const float* __restrict__ pt,
    const float* __restrict__ gq, const float* __restrict__ gkv,
    const float* __restrict__ gc,
    const float* __restrict__ Wq, const float* __restrict__ Wkv,
    const float* __restrict__ Wc, const float* __restrict__ Wout,
    unsigned short* xqn_h, unsigned short* xqn_l,
    unsigned short* xkvn_h, unsigned short* xkvn_l,
    unsigned short* ptn_h, unsigned short* ptn_l,
    unsigned short* WqT_h, unsigned short* WqT_l,
    unsigned short* WkvT_h, unsigned short* WkvT_l,
    unsigned short* WcT_h, unsigned short* WcT_l,
    unsigned short* WoT_h, unsigned short* WoT_l)
{
    const int b = blockIdx.x;
    if (b < 2048) {
        rms_body(b, x, pt, gq, gkv, gc, xqn_h, xqn_l, xkvn_h, xkvn_l, ptn_h, ptn_l);
    } else if (b < 2304) {
        int s = b - 2048; wsplit_body(Wq, WqT_h, WqT_l, 1024, 1024, s & 15, s >> 4);
    } else if (b < 2816) {
        int s = b - 2304; wsplit_body(Wkv, WkvT_h, WkvT_l, 1024, 2048, s & 31, s >> 5);
    } else if (b < 3072) {
        int s = b - 2816; wsplit_body(Wc, WcT_h, WcT_l, 1024, 1024, s & 15, s >> 4);
    } else {
        int s = b - 3072; wsplit_body(Wout, WoT_h, WoT_l, 1024, 1024, s & 15, s >> 4);
    }
}

// ====== split-bf16 MFMA GEMM: 128x128 tile, 512 thr (8 waves, 2x4) =========
// A: [1024][1024] bf16 row-major; B: [N][1024] (W^T). BK=32 (2-way banks).
// 128x128 halves L2 re-read traffic vs 128x64 (A re-read = N/128 not N/64).
__device__ __forceinline__ void gemm3p(
    const unsigned short* __restrict__ Ah, const unsigned short* __restrict__ Al,
    const unsigned short* __restrict__ Bh, const unsigned short* __restrict__ Bl,
    const float* __restrict__ bias, float* __restrict__ out, int N, int mt, int nt)
{
    __shared__ unsigned short sAh[128 * 32], sAl[128 * 32];
    __shared__ unsigned short sBh[128 * 32], sBl[128 * 32];
    const int t = threadIdx.x;
    const int lane = t & 63, w = t >> 6;        // 8 waves
    const int wm = w >> 2, wn = w & 3;          // 2x4 wave grid; wave = 64x32
    const int n16 = lane & 15, quad = lane >> 4;
    const int srow = t >> 2, scol = (t & 3) * 8;
    f32x4 zero = {0.f, 0.f, 0.f, 0.f};
    f32x4 acc[4][2];
    #pragma unroll
    for (int ms = 0; ms < 4; ++ms)
        #pragma unroll
        for (int ns = 0; ns < 2; ++ns) acc[ms][ns] = zero;

    for (int kt = 0; kt < 32; ++kt) {
        const int k0 = kt * 32;
        const size_t ga = (size_t)(mt * 128 + srow) * 1024 + k0 + scol;
        const size_t gb = (size_t)(nt * 128 + srow) * 1024 + k0 + scol;
        __syncthreads();
        gload16(Ah + ga, sAh + w * 512);   // wave w stages rows 16w..16w+15
        gload16(Al + ga, sAl + w * 512);
        gload16(Bh + gb, sBh + w * 512);
        gload16(Bl + gb, sBl + w * 512);
        __syncthreads();
        bf16x8 afh[4], afl[4], bfh[2], bfl[2];
        #pragma unroll
        for (int ms = 0; ms < 4; ++ms) {
            int r = wm * 64 + ms * 16 + n16;
            afh[ms] = *(const bf16x8*)&sAh[r * 32 + quad * 8];
            afl[ms] = *(const bf16x8*)&sAl[r * 32 + quad * 8];
        }
        #pragma unroll
        for (int ns = 0; ns < 2; ++ns) {
            int r = wn * 32 + ns * 16 + n16;
            bfh[ns] = *(const bf16x8*)&sBh[r * 32 + quad * 8];
            bfl[ns] = *(const bf16x8*)&sBl[r * 32 + quad * 8];
        }
        #pragma unroll
        for (int ms = 0; ms < 4; ++ms)
            #pragma unroll
            for (int ns = 0; ns < 2; ++ns) {
                acc[ms][ns] = MFMA(afh[ms], bfh[ns], acc[ms][ns]);
                acc[ms][ns] = MFMA(afh[ms], bfl[ns], acc[ms][ns]);
                acc[ms][ns] = MFMA(afl[ms], bfh[ns], acc[ms][ns]);
            }
    }
    #pragma unroll
    for (int ns = 0; ns < 2; ++ns) {
        const int col = nt * 128 + wn * 32 + ns * 16 + n16;
        const float bv = bias[col];
        #pragma unroll
        for (int ms = 0; ms < 4; ++ms) {
            const int row0 = mt * 128 + wm * 64 + ms * 16 + quad * 4;
            #pragma unroll
            for (int reg = 0; reg < 4; ++reg)
                out[(size_t)(row0 + reg) * N + col] = acc[ms][ns][reg] + bv;
        }
    }
}

// Q(64) | KV(128) | C(64)  -> 256 blocks x 512 thr (1 block/CU)
__global__ __launch_bounds__(512) void proj_kernel(
    const unsigned short* __restrict__ xqn_h, const unsigned short* __restrict__ xqn_l,
    const unsigned short* __restrict__ xkvn_h, const unsigned short* __restrict__ xkvn_l,
    const unsigned short* __restrict__ ptn_h, const unsigned short* __restrict__ ptn_l,
    const unsigned short* __restrict__ WqT_h, const unsigned short* __restrict__ WqT_l,
    const unsigned short* __restrict__ WkvT_h, const unsigned short* __restrict__ WkvT_l,
    const unsigned short* __restrict__ WcT_h, const unsigned short* __restrict__ WcT_l,
    const float* __restrict__ bq, const float* __restrict__ bkv,
    const float* __restrict__ bc,
    float* __restrict__ Qb, float* __restrict__ KVb, float* __restrict__ Cb)
{
    const int bid = blockIdx.x;
    if (bid < 64) {
        gemm3p(xqn_h, xqn_l, WqT_h, WqT_l, bq, Qb, 1024, bid >> 3, bid & 7);
    } else if (bid < 192) {
        int b2 = bid - 64;
        gemm3p(xkvn_h, xkvn_l, WkvT_h, WkvT_l, bkv, KVb, 2048, b2 >> 4, b2 & 15);
    } else {
        int b2 = bid - 192;
        gemm3p(ptn_h, ptn_l, WcT_h, WcT_l, bc, Cb, 1024, b2 >> 3, b2 & 7);
    }
}

// ================== prefix sums of C over rows =============================
__global__ __launch_bounds__(256) void csum_kernel(const float* __restrict__ Cb,
                                                   float* __restrict__ csum)
{
    const int cid = blockIdx.x >> 2;
    const int col = ((blockIdx.x & 3) << 8) + threadIdx.x;
    const float* p = Cb + (size_t)cid * 32 * 1024 + col;
    float s = 0.f;
    #pragma unroll 8
    for (int r = 0; r < 32; ++r) s += p[(size_t)r * 1024];
    csum[cid * 1024 + col] = s;
}

__global__ __launch_bounds__(256) void scanp_kernel(const float* __restrict__ Cb,
                                                    const float* __restrict__ csum,
                                                    float* __restrict__ Pb)
{
    const int cid = blockIdx.x >> 2;
    const int col = ((blockIdx.x & 3) << 8) + threadIdx.x;
    float run = 0.f;
    for (int c = 0; c < cid; ++c) run += csum[c * 1024 + col];
    const float* p = Cb + (size_t)cid * 32 * 1024 + col;
    float* q = Pb + (size_t)cid * 32 * 1024 + col;
    for (int r = 0; r < 32; ++r) {
        q[(size_t)r * 1024] = run;
        run += p[(size_t)r * 1024];
    }
    if (cid == 31) Pb[(size_t)1024 * 1024 + col] = run;
}

// ==== merged: A/B build (split bf16) + V transpose to bf16 [h][d][j] =======
__global__ __launch_bounds__(256) void abv_kernel(
    const float* __restrict__ Qb, const float* __restrict__ KVb,
    const float* __restrict__ Pb, const int* __restrict__ cwp,
    unsigned short* __restrict__ Aah, unsigned short* __restrict__ Aal,
    unsigned short* __restrict__ Bah, unsigned short* __restrict__ Bal,
    unsigned short* __restrict__ VT)
{
    const int b = blockIdx.x;
    if (b < 4096) {
        const int gid = b * 256 + threadIdx.x;
        const int i = gid >> 10;
        const int col = gid & 1023;
        const int h = col >> 6, dd = col & 63;
        const int cw = *cwp;
        const int E = min(i + cw, LQ);
        const int S = max(i - cw, 0);
        const float pe = Pb[(size_t)E * 1024 + col];
        const float ps = Pb[(size_t)S * 1024 + col];
        const float q = Qb[gid];
        const float k = KVb[(size_t)i * 2048 + col];
        const float scale = 0.125f;   // 64^-0.5
        const size_t base = ((size_t)(h * 1024 + i)) * 128;
        float a0 = q, a1 = q * pe;
        float b0 = k * (scale - ps), b1 = k;
        unsigned short hv;
        hv = f2bf(a0); Aah[base + dd] = hv;      Aal[base + dd] = f2bf(a0 - bf2f(hv));
        hv = f2bf(a1); Aah[base + 64 + dd] = hv; Aal[base + 64 + dd] = f2bf(a1 - bf2f(hv));
        hv = f2bf(b0); Bah[base + dd] = hv;      Bal[base + dd] = f2bf(b0 - bf2f(hv));
        hv = f2bf(b1); Bah[base + 64 + dd] = hv; Bal[base + 64 + dd] = f2bf(b1 - bf2f(hv));
    } else {
        const int s = b - 4096;
        const int h = s >> 4, j0 = (s & 15) * 64;
        __shared__ float T[64 * 65];
        const int t = threadIdx.x;
        const int tx = t & 15, ty = t >> 4;
        #pragma unroll
        for (int p = 0; p < 4; ++p) {
            int j = ty + p * 16;
            float4 v = *(const float4*)(KVb + (size_t)(j0 + j) * 2048 + 1024 + h * 64 + tx * 4);
            T[j * 65 + tx * 4 + 0] = v.x;
            T[j * 65 + tx * 4 + 1] = v.y;
            T[j * 65 + tx * 4 + 2] = v.z;
            T[j * 65 + tx * 4 + 3] = v.w;
        }
        __syncthreads();
        #pragma unroll
        for (int p = 0; p < 4; ++p) {
            int d = ty + p * 16;
            unsigned short e0 = f2bf(T[(tx * 4 + 0) * 65 + d]);
            unsigned short e1 = f2bf(T[(tx * 4 + 1) * 65 + d]);
            unsigned short e2 = f2bf(T[(tx * 4 + 2) * 65 + d]);
            unsigned short e3 = f2bf(T[(tx * 4 + 3) * 65 + d]);
            uint2 pk;
            pk.x = (unsigned)e0 | ((unsigned)e1 << 16);
            pk.y = (unsigned)e2 | ((unsigned)e3 << 16);
            *(uint2*)(VT + (size_t)(h * 64 + d) * 1024 + j0 + tx * 4) = pk;
        }
    }
}

// ============ flash attention: block = (head, 16-row i-tile) ===============
// R5 structure (measured 54 us) with A-fragments RE-LOADED each j-iteration
// (L1-hot) instead of hoisted: 32 fewer VGPRs live across softmax -> no
// scratch spill (R6's V-prefetch + hoisted A spilled: WRITE_SIZE 5->54 MB).
// 1024 blocks x 4 waves; wave w takes j-tiles w, w+4, ...; LDS combine.
// Per-CU work constant: 4 blocks give it16 in {q, 31-q, 32+q, 63-q}.
__global__ __launch_bounds__(256, 4) void attn_kernel(
    const unsigned short* __restrict__ Aah, const unsigned short* __restrict__ Aal,
    const unsigned short* __restrict__ Bah, const unsigned short* __restrict__ Bal,
    const unsigned short* __restrict__ VT,
    unsigned short* __restrict__ wvh, unsigned short* __restrict__ wvl)
{
    __shared__ unsigned short PsAll[4][16 * 68];   // per-wave P scratch
    __shared__ float cO[4][16 * 68];               // partial O (stride 68)
    __shared__ float cM[4][16], cL[4][16];

    const int t = threadIdx.x;
    const int lane = t & 63, wid = t >> 6;
    unsigned short* Ps = PsAll[wid];
    const int b = blockIdx.x;
    const int h = b & 15;
    const int q = (b >> 4) & 15;
    const int group = b >> 8;
    const int it16 = (group == 0) ? q : (group == 1) ? (31 - q)
                   : (group == 2) ? (32 + q) : (63 - q);
    const int i0 = it16 * 16;
    const int njt = (i0 >> 6) + 1;
    const int n16 = lane & 15, quad = lane >> 4;

    f32x4 zero = {0.f, 0.f, 0.f, 0.f};
    f32x4 oacc[4];
    #pragma unroll
    for (int dt = 0; dt < 4; ++dt) oacc[dt] = zero;
    float mrow[4], lrow[4];
    #pragma unroll
    for (int reg = 0; reg < 4; ++reg) { mrow[reg] = -1e30f; lrow[reg] = 0.f; }

    const size_t ar = ((size_t)(h * 1024 + i0 + n16)) * 128 + quad * 8;

    for (int jt = wid; jt < njt; jt += 4) {
        const int j0 = jt * 64;
        // A fragments (re-loaded each iteration; L1-hot, short register life)
        bf16x8 afh[4], afl[4];
        #pragma unroll
        for (int kc = 0; kc < 4; ++kc) {
            afh[kc] = *(const bf16x8*)(Aah + ar + kc * 32);
            afl[kc] = *(const bf16x8*)(Aal + ar + kc * 32);
        }
        // S = A*B^T : B fragments direct from global
        f32x4 s[4];
        #pragma unroll
        for (int jj = 0; jj < 4; ++jj) s[jj] = zero;
        #pragma unroll
        for (int jj = 0; jj < 4; ++jj) {
            const size_t br = ((size_t)(h * 1024 + j0 + jj * 16 + n16)) * 128 + quad * 8;
            #pragma unroll
            for (int kc = 0; kc < 4; ++kc) {
                bf16x8 bh = *(const bf16x8*)(Bah + br + kc * 32);
                bf16x8 bl = *(const bf16x8*)(Bal + br + kc * 32);
                s[jj] = MFMA(afh[kc], bh, s[jj]);
                s[jj] = MFMA(afh[kc], bl, s[jj]);
                s[jj] = MFMA(afl[kc], bh, s[jj]);
            }
        }
        if (jt == njt - 1) {   // diagonal tile: causal mask
            const int ibase = i0 + quad * 4;
            #pragma unroll
            for (int jj = 0; jj < 4; ++jj) {
                const int j = j0 + jj * 16 + n16;
                #pragma unroll
                for (int reg = 0; reg < 4; ++reg)
                    if (j > ibase + reg) s[jj][reg] = -1e30f;
            }
        }

        // online softmax (row = quad*4+reg; reduce across n16 lanes)
        float alpha[4];
        #pragma unroll
        for (int reg = 0; reg < 4; ++reg) {
            float mt_ = fmaxf(fmaxf(s[0][reg], s[1][reg]), fmaxf(s[2][reg], s[3][reg]));
            mt_ = fmaxf(mt_, __shfl_xor(mt_, 1));
            mt_ = fmaxf(mt_, __shfl_xor(mt_, 2));
            mt_ = fmaxf(mt_, __shfl_xor(mt_, 4));
            mt_ = fmaxf(mt_, __shfl_xor(mt_, 8));
            const float mn = fmaxf(mrow[reg], mt_);
            alpha[reg] = __expf(mrow[reg] - mn);
            mrow[reg] = mn;
            float rs = 0.f;
            #pragma unroll
            for (int jj = 0; jj < 4; ++jj) {
                float p = __expf(s[jj][reg] - mn);
                s[jj][reg] = p;
                rs += p;
            }
            rs += __shfl_xor(rs, 1); rs += __shfl_xor(rs, 2);
            rs += __shfl_xor(rs, 4); rs += __shfl_xor(rs, 8);
            lrow[reg] = lrow[reg] * alpha[reg] + rs;
        }

        // P: C-layout -> A-operand layout via per-wave LDS (no barrier)
        WAIT_LDS();   // prior Ps reads retired
        #pragma unroll
        for (int jj = 0; jj < 4; ++jj)
            #pragma unroll
            for (int reg = 0; reg < 4; ++reg)
                Ps[(quad * 4 + reg) * 68 + jj * 16 + n16] = f2bf(s[jj][reg]);
        WAIT_LDS();   // writes visible in-wave
        bf16x8 pf0 = *(const bf16x8*)&Ps[n16 * 68 + quad * 8];
        bf16x8 pf1 = *(const bf16x8*)&Ps[n16 * 68 + 32 + quad * 8];

        // PV: V fragments direct from VT[h][d][j] (late loads, low reg life)
        #pragma unroll
        for (int dt = 0; dt < 4; ++dt) {
            #pragma unroll
            for (int reg = 0; reg < 4; ++reg) oacc[dt][reg] *= alpha[reg];
            const size_t vr = ((size_t)(h * 64 + dt * 16 + n16)) * 1024 + j0 + quad * 8;
            bf16x8 vf0 = *(const bf16x8*)(VT + vr);
            bf16x8 vf1 = *(const bf16x8*)(VT + vr + 32);
            oacc[dt] = MFMA(pf0, vf0, oacc[dt]);
            oacc[dt] = MFMA(pf1, vf1, oacc[dt]);
        }
    }

    // ---- block-level combine of the 4 wave partials (in LDS) ----
    #pragma unroll
    for (int dt = 0; dt < 4; ++dt)
        #pragma unroll
        for (int reg = 0; reg < 4; ++reg)
            cO[wid][(quad * 4 + reg) * 68 + dt * 16 + n16] = oacc[dt][reg];
    if (n16 == 0) {
        #pragma unroll
        for (int reg = 0; reg < 4; ++reg) {
            cM[wid][quad * 4 + reg] = mrow[reg];
            cL[wid][quad * 4 + reg] = lrow[reg];
        }
    }
    __syncthreads();
    #pragma unroll
    for (int u = 0; u < 4; ++u) {
        const int p = u * 256 + t;
        const int r = p >> 6, d = p & 63;
        const float m0 = cM[0][r], m1 = cM[1][r], m2 = cM[2][r], m3 = cM[3][r];
        const float M = fmaxf(fmaxf(m0, m1), fmaxf(m2, m3));
        const float e0 = __expf(m0 - M), e1 = __expf(m1 - M);
        const float e2 = __expf(m2 - M), e3 = __expf(m3 - M);
        const float L = e0 * cL[0][r] + e1 * cL[1][r] + e2 * cL[2][r] + e3 * cL[3][r];
        const float o = e0 * cO[0][r * 68 + d] + e1 * cO[1][r * 68 + d]
                      + e2 * cO[2][r * 68 + d] + e3 * cO[3][r * 68 + d];
        const float v = o / L;
        const size_t oi = (size_t)(i0 + r) * 1024 + h * 64 + d;
        const unsigned short hv = f2bf(v);
        wvh[oi] = hv;
        wvl[oi] = f2bf(v - bf2f(hv));
    }
}

// ====== out GEMM: 64x64 tile, 256 thr (4 waves 2x2), 256 blocks ============
__global__ __launch_bounds__(256) void outgemm_kernel(
    const unsigned short* __restrict__ Ah, const unsigned short* __restrict__ Al,
    const unsigned short* __restrict__ Bh, const unsigned short* __restrict__ Bl,
    const float* __restrict__ bias, float* __restrict__ out)
{
    __shared__ unsigned short sAh[64 * 32], sAl[64 * 32];
    __shared__ unsigned short sBh[64 * 32], sBl[64 * 32];
    const int t = threadIdx.x;
    const int lane = t & 63, w = t >> 6;
    const int wm = w >> 1, wn = w & 1;          // 2x2 wave grid; wave = 32x32
    const int n16 = lane & 15, quad = lane >> 4;
    const int mt = blockIdx.x >> 4, nt = blockIdx.x & 15;
    const int srow = t >> 2, scol = (t & 3) * 8;
    f32x4 zero = {0.f, 0.f, 0.f, 0.f};
    f32x4 acc[2][2];
    #pragma unroll
    for (int ms = 0; ms < 2; ++ms)
        #pragma unroll
        for (int ns = 0; ns < 2; ++ns) acc[ms][ns] = zero;

    for (int kt = 0; kt < 32; ++kt) {
        const int k0 = kt * 32;
        const size_t ga = (size_t)(mt * 64 + srow) * 1024 + k0 + scol;
        const size_t gb = (size_t)(nt * 64 + srow) * 1024 + k0 + scol;
        __syncthreads();
        gload16(Ah + ga, sAh + w * 512);
        gload16(Al + ga, sAl + w * 512);
        gload16(Bh + gb, sBh + w * 512);
        gload16(Bl + gb, sBl + w * 512);
        __syncthreads();
        bf16x8 ah[2], al[2], bh[2], bl[2];
        #pragma unroll
        for (int ms = 0; ms < 2; ++ms) {
            int r = wm * 32 + ms * 16 + n16;
            ah[ms] = *(const bf16x8*)&sAh[r * 32 + quad * 8];
            al[ms] = *(const bf16x8*)&sAl[r * 32 + quad * 8];
        }
        #pragma unroll
        for (int ns = 0; ns < 2; ++ns) {
            int r = wn * 32 + ns * 16 + n16;
            bh[ns] = *(const bf16x8*)&sBh[r * 32 + quad * 8];
            bl[ns] = *(const bf16x8*)&sBl[r * 32 + quad * 8];
        }
        #pragma unroll
        for (int ms = 0; ms < 2; ++ms)
            #pragma unroll
            for (int ns = 0; ns < 2; ++ns) {
                acc[ms][ns] = MFMA(ah[ms], bh[ns], acc[ms][ns]);
                acc[ms][ns] = MFMA(ah[ms], bl[ns], acc[ms][ns]);
                acc[ms][ns] = MFMA(al[ms], bh[ns], acc[ms][ns]);
            }
    }
    #pragma unroll
    for (int ns = 0; ns < 2; ++ns) {
        const int col = nt * 64 + wn * 32 + ns * 16 + n16;
        const float bv = bias[col];
        #pragma unroll
        for (int ms = 0; ms < 2; ++ms) {
            const int row0 = mt * 64 + wm * 32 + ms * 16 + quad * 4;
            #pragma unroll
            for (int reg = 0; reg < 4; ++reg)
                out[(size_t)(row0 + reg) * 1024 + col] = acc[ms][ns][reg] + bv;
        }
    }
}

// ================================ launch ===================================
extern "C" void kernel_launch(void* const* d_in, const int* in_sizes, int n_in,
                              void* d_out, int out_size, void* d_ws, size_t ws_size,
                              hipStream_t stream) {
    (void)in_sizes; (void)n_in; (void)out_size; (void)ws_size;
    const float* x    = (const float*)d_in[0];
    const float* pt   = (const float*)d_in[1];
    const float* gq   = (const float*)d_in[3];
    const float* Wq   = (const float*)d_in[4];
    const float* bq   = (const float*)d_in[5];
    const float* gkv  = (const float*)d_in[6];
    const float* Wkv  = (const float*)d_in[7];
    const float* bkv  = (const float*)d_in[8];
    const float* gc   = (const float*)d_in[9];
    const float* Wc   = (const float*)d_in[10];
    const float* bc   = (const float*)d_in[11];
    const float* Wout = (const float*)d_in[12];
    const float* bout = (const float*)d_in[13];
    const int*   cw   = (const int*)d_in[14];
    float* out = (float*)d_out;

    char* W = (char*)d_ws;
    const size_t MB = 1u << 20;
    #define US(off) ((unsigned short*)(W + (size_t)(off)))
    #define FP(off) ((float*)(W + (size_t)(off)))
    // prep pool (dead after proj):
    unsigned short* xqn_h  = US(0 * MB);
    unsigned short* xqn_l  = US(2 * MB);
    unsigned short* xkvn_h = US(4 * MB);
    unsigned short* xkvn_l = US(6 * MB);
    unsigned short* ptn_h  = US(8 * MB);
    unsigned short* ptn_l  = US(10 * MB);
    unsigned short* WqT_h  = US(12 * MB);
    unsigned short* WqT_l  = US(14 * MB);
    unsigned short* WkvT_h = US(16 * MB);
    unsigned short* WkvT_l = US(20 * MB);
    unsigned short* WcT_h  = US(24 * MB);
    unsigned short* WcT_l  = US(26 * MB);
    unsigned short* WoT_h  = US(28 * MB);   // live till end
    unsigned short* WoT_l  = US(30 * MB);
    float* Qb   = FP(32 * MB);   // 4 MB
    float* KVb  = FP(36 * MB);   // 8 MB
    float* Cb   = FP(44 * MB);   // 4 MB
    float* Pb   = FP(48 * MB);   // 4.004 MB
    float* csum = FP(52 * MB + 256 * 1024);   // 128 KB
    // reuse of dead prep pool:
    unsigned short* Aah = US(0 * MB);    // 4 MB each
    unsigned short* Aal = US(4 * MB);
    unsigned short* Bah = US(8 * MB);
    unsigned short* Bal = US(12 * MB);
    unsigned short* VTb = US(16 * MB);   // 2 MB
    unsigned short* wv_h = US(18 * MB);  // 2 MB
    unsigned short* wv_l = US(20 * MB);  // 2 MB
    #undef US
    #undef FP

    hipLaunchKernelGGL(prep_kernel, dim3(3328), dim3(256), 0, stream,
                       x, pt, gq, gkv, gc, Wq, Wkv, Wc, Wout,
                       xqn_h, xqn_l, xkvn_h, xkvn_l, ptn_h, ptn_l,
                       WqT_h, WqT_l, WkvT_h, WkvT_l, WcT_h, WcT_l, WoT_h, WoT_l);
    hipLaunchKernelGGL(proj_kernel, dim3(256), dim3(512), 0, stream,
                       xqn_h, xqn_l, xkvn_h, xkvn_l, ptn_h, ptn_l,
                       WqT_h, WqT_l, WkvT_h, WkvT_l, WcT_h, WcT_l,
                       bq, bkv, bc, Qb, KVb, Cb);
    hipLaunchKernelGGL(csum_kernel, dim3(128), dim3(256), 0, stream, Cb, csum);
    hipLaunchKernelGGL(scanp_kernel, dim3(128), dim3(256), 0, stream, Cb, csum, Pb);
    hipLaunchKernelGGL(abv_kernel, dim3(4352), dim3(256), 0, stream,
                       Qb, KVb, Pb, cw, Aah, Aal, Bah, Bal, VTb);
    hipLaunchKernelGGL(attn_kernel, dim3(1024), dim3(256), 0, stream,
                       Aah, Aal, Bah, Bal, VTb, wv_h, wv_l);
    hipLaunchKernelGGL(outgemm_kernel, dim3(256), dim3(256), 0, stream,
                       wv_h, wv_l, WoT_h, WoT_l, bout, out);
}

// Round 8
// 223.071 us; speedup vs baseline: 1.0725x; 1.0497x over previous
//
#include <hip/hip_runtime.h>

#define LQ 1024
#define DM 1024

// Split-bf16: x = hi + lo (both bf16); GEMMs run 3 MFMA passes (hh+hl+lh)
// for ~2^-17 relative precision (scores reach ~±100; softmax needs abs
// score error << 1e-1).

typedef __attribute__((ext_vector_type(8))) short bf16x8;
typedef __attribute__((ext_vector_type(4))) float f32x4;

#define MFMA(a, b, c) __builtin_amdgcn_mfma_f32_16x16x32_bf16((a), (b), (c), 0, 0, 0)
#define WAIT_LDS() __builtin_amdgcn_s_waitcnt(0xC07F)   // lgkmcnt(0) only

__device__ __forceinline__ unsigned short f2bf(float x) {
    unsigned int u = __float_as_uint(x);
    return (unsigned short)((u + 0x7FFFu + ((u >> 16) & 1u)) >> 16);
}
__device__ __forceinline__ float bf2f(unsigned short h) {
    return __uint_as_float(((unsigned int)h) << 16);
}
__device__ __forceinline__ void gload16(const void* gp, void* lp) {
    __builtin_amdgcn_global_load_lds(
        (const __attribute__((address_space(1))) void*)gp,
        (__attribute__((address_space(3))) void*)lp, 16, 0, 0);
}
__device__ __forceinline__ void store_split4(unsigned short* ph, unsigned short* pl,
                                             float4 v) {
    unsigned short h0 = f2bf(v.x), h1 = f2bf(v.y), h2 = f2bf(v.z), h3 = f2bf(v.w);
    uint2 a;
    a.x = (unsigned)h0 | ((unsigned)h1 << 16);
    a.y = (unsigned)h2 | ((unsigned)h3 << 16);
    *(uint2*)ph = a;
    unsigned short l0 = f2bf(v.x - bf2f(h0)), l1 = f2bf(v.y - bf2f(h1));
    unsigned short l2 = f2bf(v.z - bf2f(h2)), l3 = f2bf(v.w - bf2f(h3));
    uint2 b;
    b.x = (unsigned)l0 | ((unsigned)l1 << 16);
    b.y = (unsigned)l2 | ((unsigned)l3 << 16);
    *(uint2*)pl = b;
}

// ==================== merged prep: RMSNorm + 4 weight splits ===============
__device__ __forceinline__ void rms_body(
    int row, const float* __restrict__ x, const float* __restrict__ pt,
    const float* __restrict__ gq, const float* __restrict__ gkv,
    const float* __restrict__ gc,
    unsigned short* xqn_h, unsigned short* xqn_l,
    unsigned short* xkvn_h, unsigned short* xkvn_l,
    unsigned short* ptn_h, unsigned short* ptn_l)
{
    const int t = threadIdx.x;
    const bool isx = row < LQ;
    const float* src = isx ? (x + (size_t)row * DM)
                           : (pt + (size_t)(row - LQ) * DM);
    float4 v = ((const float4*)src)[t];
    float ss = v.x*v.x + v.y*v.y + v.z*v.z + v.w*v.w;
    #pragma unroll
    for (int o = 32; o > 0; o >>= 1) ss += __shfl_down(ss, o);
    __shared__ float red[4];
    if ((t & 63) == 0) red[t >> 6] = ss;
    __syncthreads();
    const float r = rsqrtf((red[0] + red[1] + red[2] + red[3]) * (1.0f / DM)
                           + 1.1920929e-07f);
    const size_t base = (size_t)(isx ? row : row - LQ) * DM + t * 4;
    if (isx) {
        float4 g1 = ((const float4*)gq)[t];
        float4 g2 = ((const float4*)gkv)[t];
        float4 y1, y2;
        y1.x = v.x*r*g1.x; y1.y = v.y*r*g1.y; y1.z = v.z*r*g1.z; y1.w = v.w*r*g1.w;
        y2.x = v.x*r*g2.x; y2.y = v.y*r*g2.y; y2.z = v.z*r*g2.z; y2.w = v.w*r*g2.w;
        store_split4(xqn_h + base, xqn_l + base, y1);
        store_split4(xkvn_h + base, xkvn_l + base, y2);
    } else {
        float4 g = ((const float4*)gc)[t];
        float4 y;
        y.x = v.x*r*g.x; y.y = v.y*r*g.y; y.z = v.z*r*g.z; y.w = v.w*r*g.w;
        store_split4(ptn_h + base, ptn_l + base, y);
    }
}

__device__ __forceinline__ void wsplit_body(
    const float* __restrict__ in, unsigned short* oh, unsigned short* ol,
    int K, int N, int bx, int by)
{
    __shared__ float T[64 * 65];
    const int t = threadIdx.x;
    const int tx = t & 15, ty = t >> 4;
    const int c0 = bx * 64, r0 = by * 64;
    #pragma unroll
    for (int p = 0; p < 4; ++p) {
        int row = ty + p * 16;
        float4 v = *(const float4*)(in + (size_t)(r0 + row) * N + c0 + tx * 4);
        T[row * 65 + tx * 4 + 0] = v.x;
        T[row * 65 + tx * 4 + 1] = v.y;
        T[row * 65 + tx * 4 + 2] = v.z;
        T[row * 65 + tx * 4 + 3] = v.w;
    }
    __syncthreads();
    #pragma unroll
    for (int p = 0; p < 4; ++p) {
        int n = ty + p * 16;
        float4 w;
        w.x = T[(tx * 4 + 0) * 65 + n];
        w.y = T[(tx * 4 + 1) * 65 + n];
        w.z = T[(tx * 4 + 2) * 65 + n];
        w.w = T[(tx * 4 + 3) * 65 + n];
        size_t o = (size_t)(c0 + n) * K + r0 + tx * 4;
        store_split4(oh + o, ol + o, w);
    }
}

__global__ __launch_bounds__(256) void prep_kernel(
    const float* __restrict__ x, const float* __restrict__ pt,
    const float* __restrict__ gq, const float* __restrict__ gkv,
    const float* __restrict__ gc,
    const float* __restrict__ Wq, const float* __restrict__ Wkv,
    const float* __restrict__ Wc, const float* __restrict__ Wout,
    unsigned short* xqn_h, unsigned short* xqn_l,
    unsigned short* xkvn_h, unsigned short* xkvn_l,
    unsigned short* ptn_h, unsigned short* ptn_l,
    unsigned short* WqT_h, unsigned short* WqT_l,
    unsigned short* WkvT_h, unsigned short* WkvT_l,
    unsigned short* WcT_h, unsigned short* WcT_l,
    unsigned short* WoT_h, unsigned short* WoT_l)
{
    const int b = blockIdx.x;
    if (b < 2048) {
        rms_body(b, x, pt, gq, gkv, gc, xqn_h, xqn_l, xkvn_h, xkvn_l, ptn_h, ptn_l);
    } else if (b < 2304) {
        int s = b - 2048; wsplit_body(Wq, WqT_h, WqT_l, 1024, 1024, s & 15, s >> 4);
    } else if (b < 2816) {
        int s = b - 2304; wsplit_body(Wkv, WkvT_h, WkvT_l, 1024, 2048, s & 31, s >> 5);
    } else if (b < 3072) {
        int s = b - 2816; wsplit_body(Wc, WcT_h, WcT_l, 1024, 1024, s & 15, s >> 4);
    } else {
        int s = b - 3072; wsplit_body(Wout, WoT_h, WoT_l, 1024, 1024, s & 15, s >> 4);
    }
}

// ====== split-bf16 MFMA GEMM: 128x64 tile, 256 thr (4 waves, 2x2) ==========
// (R5 measured-best proj shape: 512 blocks -> 2 blocks/CU barrier overlap)
__device__ __forceinline__ void gemm3p(
    const unsigned short* __restrict__ Ah, const unsigned short* __restrict__ Al,
    const unsigned short* __restrict__ Bh, const unsigned short* __restrict__ Bl,
    const float* __restrict__ bias, float* __restrict__ out, int N, int mt, int nt)
{
    __shared__ unsigned short sAh[128 * 32], sAl[128 * 32];
    __shared__ unsigned short sBh[64 * 32], sBl[64 * 32];
    const int t = threadIdx.x;
    const int lane = t & 63, w = t >> 6;
    const int wm = w >> 1, wn = w & 1;          // 2x2 wave grid; wave = 64x32
    const int n16 = lane & 15, quad = lane >> 4;
    const int srow = t >> 2, scol = (t & 3) * 8;
    f32x4 zero = {0.f, 0.f, 0.f, 0.f};
    f32x4 acc[4][2];
    #pragma unroll
    for (int ms = 0; ms < 4; ++ms)
        #pragma unroll
        for (int ns = 0; ns < 2; ++ns) acc[ms][ns] = zero;

    for (int kt = 0; kt < 32; ++kt) {
        const int k0 = kt * 32;
        __syncthreads();
        #pragma unroll
        for (int p = 0; p < 2; ++p) {   // A: 128 rows = 2 x 64-row calls
            const size_t ga = (size_t)(mt * 128 + srow + p * 64) * 1024 + k0 + scol;
            const int lb = w * 512 + p * 2048;
            gload16(Ah + ga, sAh + lb);
            gload16(Al + ga, sAl + lb);
        }
        {   // B: 64 rows = 1 call
            const size_t gb = (size_t)(nt * 64 + srow) * 1024 + k0 + scol;
            gload16(Bh + gb, sBh + w * 512);
            gload16(Bl + gb, sBl + w * 512);
        }
        __syncthreads();
        bf16x8 afh[4], afl[4], bfh[2], bfl[2];
        #pragma unroll
        for (int ms = 0; ms < 4; ++ms) {
            int r = wm * 64 + ms * 16 + n16;
            afh[ms] = *(const bf16x8*)&sAh[r * 32 + quad * 8];
            afl[ms] = *(const bf16x8*)&sAl[r * 32 + quad * 8];
        }
        #pragma unroll
        for (int ns = 0; ns < 2; ++ns) {
            int r = wn * 32 + ns * 16 + n16;
            bfh[ns] = *(const bf16x8*)&sBh[r * 32 + quad * 8];
            bfl[ns] = *(const bf16x8*)&sBl[r * 32 + quad * 8];
        }
        #pragma unroll
        for (int ms = 0; ms < 4; ++ms)
            #pragma unroll
            for (int ns = 0; ns < 2; ++ns) {
                acc[ms][ns] = MFMA(afh[ms], bfh[ns], acc[ms][ns]);
                acc[ms][ns] = MFMA(afh[ms], bfl[ns], acc[ms][ns]);
                acc[ms][ns] = MFMA(afl[ms], bfh[ns], acc[ms][ns]);
            }
    }
    #pragma unroll
    for (int ns = 0; ns < 2; ++ns) {
        const int col = nt * 64 + wn * 32 + ns * 16 + n16;
        const float bv = bias[col];
        #pragma unroll
        for (int ms = 0; ms < 4; ++ms) {
            const int row0 = mt * 128 + wm * 64 + ms * 16 + quad * 4;
            #pragma unroll
            for (int reg = 0; reg < 4; ++reg)
                out[(size_t)(row0 + reg) * N + col] = acc[ms][ns][reg] + bv;
        }
    }
}

// Q(128) | KV(256) | C(128)  -> 512 blocks, 2 blocks/CU
__global__ __launch_bounds__(256) void proj_kernel(
    const unsigned short* __restrict__ xqn_h, const unsigned short* __restrict__ xqn_l,
    const unsigned short* __restrict__ xkvn_h, const unsigned short* __restrict__ xkvn_l,
    const unsigned short* __restrict__ ptn_h, const unsigned short* __restrict__ ptn_l,
    const unsigned short* __restrict__ WqT_h, const unsigned short* __restrict__ WqT_l,
    const unsigned short* __restrict__ WkvT_h, const unsigned short* __restrict__ WkvT_l,
    const unsigned short* __restrict__ WcT_h, const unsigned short* __restrict__ WcT_l,
    const float* __restrict__ bq, const float* __restrict__ bkv,
    const float* __restrict__ bc,
    float* __restrict__ Qb, float* __restrict__ KVb, float* __restrict__ Cb)
{
    const int bid = blockIdx.x;
    if (bid < 128) {
        gemm3p(xqn_h, xqn_l, WqT_h, WqT_l, bq, Qb, 1024, bid >> 4, bid & 15);
    } else if (bid < 384) {
        int b2 = bid - 128;
        gemm3p(xkvn_h, xkvn_l, WkvT_h, WkvT_l, bkv, KVb, 2048, b2 >> 5, b2 & 31);
    } else {
        int b2 = bid - 384;
        gemm3p(ptn_h, ptn_l, WcT_h, WcT_l, bc, Cb, 1024, b2 >> 4, b2 & 15);
    }
}

// ================== prefix sums of C over rows =============================
__global__ __launch_bounds__(256) void csum_kernel(const float* __restrict__ Cb,
                                                   float* __restrict__ csum)
{
    const int cid = blockIdx.x >> 2;
    const int col = ((blockIdx.x & 3) << 8) + threadIdx.x;
    const float* p = Cb + (size_t)cid * 32 * 1024 + col;
    float s = 0.f;
    #pragma unroll 8
    for (int r = 0; r < 32; ++r) s += p[(size_t)r * 1024];
    csum[cid * 1024 + col] = s;
}

__global__ __launch_bounds__(256) void scanp_kernel(const float* __restrict__ Cb,
                                                    const float* __restrict__ csum,
                                                    float* __restrict__ Pb)
{
    const int cid = blockIdx.x >> 2;
    const int col = ((blockIdx.x & 3) << 8) + threadIdx.x;
    float run = 0.f;
    for (int c = 0; c < cid; ++c) run += csum[c * 1024 + col];
    const float* p = Cb + (size_t)cid * 32 * 1024 + col;
    float* q = Pb + (size_t)cid * 32 * 1024 + col;
    for (int r = 0; r < 32; ++r) {
        q[(size_t)r * 1024] = run;
        run += p[(size_t)r * 1024];
    }
    if (cid == 31) Pb[(size_t)1024 * 1024 + col] = run;
}

// ==== merged: A/B build (split bf16) + V transpose to bf16 [h][d][j] =======
__global__ __launch_bounds__(256) void abv_kernel(
    const float* __restrict__ Qb, const float* __restrict__ KVb,
    const float* __restrict__ Pb, const int* __restrict__ cwp,
    unsigned short* __restrict__ Aah, unsigned short* __restrict__ Aal,
    unsigned short* __restrict__ Bah, unsigned short* __restrict__ Bal,
    unsigned short* __restrict__ VT)
{
    const int b = blockIdx.x;
    if (b < 4096) {
        const int gid = b * 256 + threadIdx.x;
        const int i = gid >> 10;
        const int col = gid & 1023;
        const int h = col >> 6, dd = col & 63;
        const int cw = *cwp;
        const int E = min(i + cw, LQ);
        const int S = max(i - cw, 0);
        const float pe = Pb[(size_t)E * 1024 + col];
        const float ps = Pb[(size_t)S * 1024 + col];
        const float q = Qb[gid];
        const float k = KVb[(size_t)i * 2048 + col];
        const float scale = 0.125f;   // 64^-0.5
        const size_t base = ((size_t)(h * 1024 + i)) * 128;
        float a0 = q, a1 = q * pe;
        float b0 = k * (scale - ps), b1 = k;
        unsigned short hv;
        hv = f2bf(a0); Aah[base + dd] = hv;      Aal[base + dd] = f2bf(a0 - bf2f(hv));
        hv = f2bf(a1); Aah[base + 64 + dd] = hv; Aal[base + 64 + dd] = f2bf(a1 - bf2f(hv));
        hv = f2bf(b0); Bah[base + dd] = hv;      Bal[base + dd] = f2bf(b0 - bf2f(hv));
        hv = f2bf(b1); Bah[base + 64 + dd] = hv; Bal[base + 64 + dd] = f2bf(b1 - bf2f(hv));
    } else {
        const int s = b - 4096;
        const int h = s >> 4, j0 = (s & 15) * 64;
        __shared__ float T[64 * 65];
        const int t = threadIdx.x;
        const int tx = t & 15, ty = t >> 4;
        #pragma unroll
        for (int p = 0; p < 4; ++p) {
            int j = ty + p * 16;
            float4 v = *(const float4*)(KVb + (size_t)(j0 + j) * 2048 + 1024 + h * 64 + tx * 4);
            T[j * 65 + tx * 4 + 0] = v.x;
            T[j * 65 + tx * 4 + 1] = v.y;
            T[j * 65 + tx * 4 + 2] = v.z;
            T[j * 65 + tx * 4 + 3] = v.w;
        }
        __syncthreads();
        #pragma unroll
        for (int p = 0; p < 4; ++p) {
            int d = ty + p * 16;
            unsigned short e0 = f2bf(T[(tx * 4 + 0) * 65 + d]);
            unsigned short e1 = f2bf(T[(tx * 4 + 1) * 65 + d]);
            unsigned short e2 = f2bf(T[(tx * 4 + 2) * 65 + d]);
            unsigned short e3 = f2bf(T[(tx * 4 + 3) * 65 + d]);
            uint2 pk;
            pk.x = (unsigned)e0 | ((unsigned)e1 << 16);
            pk.y = (unsigned)e2 | ((unsigned)e3 << 16);
            *(uint2*)(VT + (size_t)(h * 64 + d) * 1024 + j0 + tx * 4) = pk;
        }
    }
}

// ============ flash attention: block = (head, 16-row i-tile) ===============
// R7 mapping, but load-latency de-serialized: __launch_bounds__(256,2) lifts
// the VGPR cap (64 -> ~220) so ALL 32 B-fragment loads batch in flight per
// j-iteration (R7: VGPR=64 forced ~8 sequential ~250-cyc L2 round-trips ->
// 78 cyc/load measured). A-fragments hoisted (affordable now, no spill at
// this budget). 1024 blocks x 4 waves, 2 blocks/CU.
__global__ __launch_bounds__(256, 2) void attn_kernel(
    const unsigned short* __restrict__ Aah, const unsigned short* __restrict__ Aal,
    const unsigned short* __restrict__ Bah, const unsigned short* __restrict__ Bal,
    const unsigned short* __restrict__ VT,
    unsigned short* __restrict__ wvh, unsigned short* __restrict__ wvl)
{
    __shared__ unsigned short PsAll[4][16 * 68];   // per-wave P scratch
    __shared__ float cO[4][16 * 68];               // partial O (stride 68)
    __shared__ float cM[4][16], cL[4][16];

    const int t = threadIdx.x;
    const int lane = t & 63, wid = t >> 6;
    unsigned short* Ps = PsAll[wid];
    const int b = blockIdx.x;
    const int h = b & 15;
    const int q = (b >> 4) & 15;
    const int group = b >> 8;
    const int it16 = (group == 0) ? q : (group == 1) ? (31 - q)
                   : (group == 2) ? (32 + q) : (63 - q);
    const int i0 = it16 * 16;
    const int njt = (i0 >> 6) + 1;
    const int n16 = lane & 15, quad = lane >> 4;

    // A fragments hoisted (row n16, k chunk kc*32 + quad*8)
    bf16x8 afh[4], afl[4];
    {
        const size_t ar = ((size_t)(h * 1024 + i0 + n16)) * 128 + quad * 8;
        #pragma unroll
        for (int kc = 0; kc < 4; ++kc) {
            afh[kc] = *(const bf16x8*)(Aah + ar + kc * 32);
            afl[kc] = *(const bf16x8*)(Aal + ar + kc * 32);
        }
    }

    f32x4 zero = {0.f, 0.f, 0.f, 0.f};
    f32x4 oacc[4];
    #pragma unroll
    for (int dt = 0; dt < 4; ++dt) oacc[dt] = zero;
    float mrow[4], lrow[4];
    #pragma unroll
    for (int reg = 0; reg < 4; ++reg) { mrow[reg] = -1e30f; lrow[reg] = 0.f; }

    for (int jt = wid; jt < njt; jt += 4) {
        const int j0 = jt * 64;

        // batch-load ALL B fragments first (32 loads in flight, 1 drain)
        bf16x8 bh[4][4], bl[4][4];
        #pragma unroll
        for (int jj = 0; jj < 4; ++jj) {
            const size_t br = ((size_t)(h * 1024 + j0 + jj * 16 + n16)) * 128 + quad * 8;
            #pragma unroll
            for (int kc = 0; kc < 4; ++kc) {
                bh[jj][kc] = *(const bf16x8*)(Bah + br + kc * 32);
                bl[jj][kc] = *(const bf16x8*)(Bal + br + kc * 32);
            }
        }

        // S = A*B^T, 3-pass split
        f32x4 s[4];
        #pragma unroll
        for (int jj = 0; jj < 4; ++jj) s[jj] = zero;
        #pragma unroll
        for (int jj = 0; jj < 4; ++jj)
            #pragma unroll
            for (int kc = 0; kc < 4; ++kc) {
                s[jj] = MFMA(afh[kc], bh[jj][kc], s[jj]);
                s[jj] = MFMA(afh[kc], bl[jj][kc], s[jj]);
                s[jj] = MFMA(afl[kc], bh[jj][kc], s[jj]);
            }

        if (jt == njt - 1) {   // diagonal tile: causal mask
            const int ibase = i0 + quad * 4;
            #pragma unroll
            for (int jj = 0; jj < 4; ++jj) {
                const int j = j0 + jj * 16 + n16;
                #pragma unroll
                for (int reg = 0; reg < 4; ++reg)
                    if (j > ibase + reg) s[jj][reg] = -1e30f;
            }
        }

        // online softmax (row = quad*4+reg; reduce across n16 lanes)
        float alpha[4];
        #pragma unroll
        for (int reg = 0; reg < 4; ++reg) {
            float mt_ = fmaxf(fmaxf(s[0][reg], s[1][reg]), fmaxf(s[2][reg], s[3][reg]));
            mt_ = fmaxf(mt_, __shfl_xor(mt_, 1));
            mt_ = fmaxf(mt_, __shfl_xor(mt_, 2));
            mt_ = fmaxf(mt_, __shfl_xor(mt_, 4));
            mt_ = fmaxf(mt_, __shfl_xor(mt_, 8));
            const float mn = fmaxf(mrow[reg], mt_);
            alpha[reg] = __expf(mrow[reg] - mn);
            mrow[reg] = mn;
            float rs = 0.f;
            #pragma unroll
            for (int jj = 0; jj < 4; ++jj) {
                float p = __expf(s[jj][reg] - mn);
                s[jj][reg] = p;
                rs += p;
            }
            rs += __shfl_xor(rs, 1); rs += __shfl_xor(rs, 2);
            rs += __shfl_xor(rs, 4); rs += __shfl_xor(rs, 8);
            lrow[reg] = lrow[reg] * alpha[reg] + rs;
        }

        // P: C-layout -> A-operand layout via per-wave LDS (no barrier)
        WAIT_LDS();   // prior Ps reads retired
        #pragma unroll
        for (int jj = 0; jj < 4; ++jj)
            #pragma unroll
            for (int reg = 0; reg < 4; ++reg)
                Ps[(quad * 4 + reg) * 68 + jj * 16 + n16] = f2bf(s[jj][reg]);
        WAIT_LDS();   // writes visible in-wave
        bf16x8 pf0 = *(const bf16x8*)&Ps[n16 * 68 + quad * 8];
        bf16x8 pf1 = *(const bf16x8*)&Ps[n16 * 68 + 32 + quad * 8];

        // PV: V fragments direct from VT[h][d][j]
        #pragma unroll
        for (int dt = 0; dt < 4; ++dt) {
            #pragma unroll
            for (int reg = 0; reg < 4; ++reg) oacc[dt][reg] *= alpha[reg];
            const size_t vr = ((size_t)(h * 64 + dt * 16 + n16)) * 1024 + j0 + quad * 8;
            bf16x8 vf0 = *(const bf16x8*)(VT + vr);
            bf16x8 vf1 = *(const bf16x8*)(VT + vr + 32);
            oacc[dt] = MFMA(pf0, vf0, oacc[dt]);
            oacc[dt] = MFMA(pf1, vf1, oacc[dt]);
        }
    }

    // ---- block-level combine of the 4 wave partials (in LDS) ----
    #pragma unroll
    for (int dt = 0; dt < 4; ++dt)
        #pragma unroll
        for (int reg = 0; reg < 4; ++reg)
            cO[wid][(quad * 4 + reg) * 68 + dt * 16 + n16] = oacc[dt][reg];
    if (n16 == 0) {
        #pragma unroll
        for (int reg = 0; reg < 4; ++reg) {
            cM[wid][quad * 4 + reg] = mrow[reg];
            cL[wid][quad * 4 + reg] = lrow[reg];
        }
    }
    __syncthreads();
    #pragma unroll
    for (int u = 0; u < 4; ++u) {
        const int p = u * 256 + t;
        const int r = p >> 6, d = p & 63;
        const float m0 = cM[0][r], m1 = cM[1][r], m2 = cM[2][r], m3 = cM[3][r];
        const float M = fmaxf(fmaxf(m0, m1), fmaxf(m2, m3));
        const float e0 = __expf(m0 - M), e1 = __expf(m1 - M);
        const float e2 = __expf(m2 - M), e3 = __expf(m3 - M);
        const float L = e0 * cL[0][r] + e1 * cL[1][r] + e2 * cL[2][r] + e3 * cL[3][r];
        const float o = e0 * cO[0][r * 68 + d] + e1 * cO[1][r * 68 + d]
                      + e2 * cO[2][r * 68 + d] + e3 * cO[3][r * 68 + d];
        const float v = o / L;
        const size_t oi = (size_t)(i0 + r) * 1024 + h * 64 + d;
        const unsigned short hv = f2bf(v);
        wvh[oi] = hv;
        wvl[oi] = f2bf(v - bf2f(hv));
    }
}

// ====== out GEMM: 64x32 tile, 128 thr (2 waves), 512 blocks (R5 shape) =====
__global__ __launch_bounds__(128) void outgemm_kernel(
    const unsigned short* __restrict__ Ah, const unsigned short* __restrict__ Al,
    const unsigned short* __restrict__ Bh, const unsigned short* __restrict__ Bl,
    const float* __restrict__ bias, float* __restrict__ out)
{
    __shared__ unsigned short sAh[64 * 32], sAl[64 * 32];
    __shared__ unsigned short sBh[32 * 32], sBl[32 * 32];
    const int t = threadIdx.x;
    const int lane = t & 63, w = t >> 6;
    const int n16 = lane & 15, quad = lane >> 4;
    const int mt = blockIdx.x >> 5, nt = blockIdx.x & 31;
    const int srow = t >> 2, scol = (t & 3) * 8;
    f32x4 zero = {0.f, 0.f, 0.f, 0.f};
    f32x4 acc[2][2];
    #pragma unroll
    for (int ms = 0; ms < 2; ++ms)
        #pragma unroll
        for (int ns = 0; ns < 2; ++ns) acc[ms][ns] = zero;

    for (int kt = 0; kt < 32; ++kt) {
        const int k0 = kt * 32;
        __syncthreads();
        #pragma unroll
        for (int p = 0; p < 2; ++p) {   // A: 64 rows = 2 x 32-row calls
            const size_t ga = (size_t)(mt * 64 + srow + p * 32) * 1024 + k0 + scol;
            const int lb = w * 512 + p * 1024;
            gload16(Ah + ga, sAh + lb);
            gload16(Al + ga, sAl + lb);
        }
        {   // B: 32 rows = 1 call
            const size_t gb = (size_t)(nt * 32 + srow) * 1024 + k0 + scol;
            gload16(Bh + gb, sBh + w * 512);
            gload16(Bl + gb, sBl + w * 512);
        }
        __syncthreads();
        bf16x8 ah[2], al[2], bh[2], bl[2];
        #pragma unroll
        for (int ms = 0; ms < 2; ++ms) {
            int r = w * 32 + ms * 16 + n16;
            ah[ms] = *(const bf16x8*)&sAh[r * 32 + quad * 8];
            al[ms] = *(const bf16x8*)&sAl[r * 32 + quad * 8];
        }
        #pragma unroll
        for (int ns = 0; ns < 2; ++ns) {
            int r = ns * 16 + n16;
            bh[ns] = *(const bf16x8*)&sBh[r * 32 + quad * 8];
            bl[ns] = *(const bf16x8*)&sBl[r * 32 + quad * 8];
        }
        #pragma unroll
        for (int ms = 0; ms < 2; ++ms)
            #pragma unroll
            for (int ns = 0; ns < 2; ++ns) {
                acc[ms][ns] = MFMA(ah[ms], bh[ns], acc[ms][ns]);
                acc[ms][ns] = MFMA(ah[ms], bl[ns], acc[ms][ns]);
                acc[ms][ns] = MFMA(al[ms], bh[ns], acc[ms][ns]);
            }
    }
    #pragma unroll
    for (int ns = 0; ns < 2; ++ns) {
        const int col = nt * 32 + ns * 16 + n16;
        const float bv = bias[col];
        #pragma unroll
        for (int ms = 0; ms < 2; ++ms) {
            const int row0 = mt * 64 + w * 32 + ms * 16 + quad * 4;
            #pragma unroll
            for (int reg = 0; reg < 4; ++reg)
                out[(size_t)(row0 + reg) * 1024 + col] = acc[ms][ns][reg] + bv;
        }
    }
}

// ================================ launch ===================================
extern "C" void kernel_launch(void* const* d_in, const int* in_sizes, int n_in,
                              void* d_out, int out_size, void* d_ws, size_t ws_size,
                              hipStream_t stream) {
    (void)in_sizes; (void)n_in; (void)out_size; (void)ws_size;
    const float* x    = (const float*)d_in[0];
    const float* pt   = (const float*)d_in[1];
    const float* gq   = (const float*)d_in[3];
    const float* Wq   = (const float*)d_in[4];
    const float* bq   = (const float*)d_in[5];
    const float* gkv  = (const float*)d_in[6];
    const float* Wkv  = (const float*)d_in[7];
    const float* bkv  = (const float*)d_in[8];
    const float* gc   = (const float*)d_in[9];
    const float* Wc   = (const float*)d_in[10];
    const float* bc   = (const float*)d_in[11];
    const float* Wout = (const float*)d_in[12];
    const float* bout = (const float*)d_in[13];
    const int*   cw   = (const int*)d_in[14];
    float* out = (float*)d_out;

    char* W = (char*)d_ws;
    const size_t MB = 1u << 20;
    #define US(off) ((unsigned short*)(W + (size_t)(off)))
    #define FP(off) ((float*)(W + (size_t)(off)))
    // prep pool (dead after proj):
    unsigned short* xqn_h  = US(0 * MB);
    unsigned short* xqn_l  = US(2 * MB);
    unsigned short* xkvn_h = US(4 * MB);
    unsigned short* xkvn_l = US(6 * MB);
    unsigned short* ptn_h  = US(8 * MB);
    unsigned short* ptn_l  = US(10 * MB);
    unsigned short* WqT_h  = US(12 * MB);
    unsigned short* WqT_l  = US(14 * MB);
    unsigned short* WkvT_h = US(16 * MB);
    unsigned short* WkvT_l = US(20 * MB);
    unsigned short* WcT_h  = US(24 * MB);
    unsigned short* WcT_l  = US(26 * MB);
    unsigned short* WoT_h  = US(28 * MB);   // live till end
    unsigned short* WoT_l  = US(30 * MB);
    float* Qb   = FP(32 * MB);   // 4 MB
    float* KVb  = FP(36 * MB);   // 8 MB
    float* Cb   = FP(44 * MB);   // 4 MB
    float* Pb   = FP(48 * MB);   // 4.004 MB
    float* csum = FP(52 * MB + 256 * 1024);   // 128 KB
    // reuse of dead prep pool:
    unsigned short* Aah = US(0 * MB);    // 4 MB each
    unsigned short* Aal = US(4 * MB);
    unsigned short* Bah = US(8 * MB);
    unsigned short* Bal = US(12 * MB);
    unsigned short* VTb = US(16 * MB);   // 2 MB
    unsigned short* wv_h = US(18 * MB);  // 2 MB
    unsigned short* wv_l = US(20 * MB);  // 2 MB
    #undef US
    #undef FP

    hipLaunchKernelGGL(prep_kernel, dim3(3328), dim3(256), 0, stream,
                       x, pt, gq, gkv, gc, Wq, Wkv, Wc, Wout,
                       xqn_h, xqn_l, xkvn_h, xkvn_l, ptn_h, ptn_l,
                       WqT_h, WqT_l, WkvT_h, WkvT_l, WcT_h, WcT_l, WoT_h, WoT_l);
    hipLaunchKernelGGL(proj_kernel, dim3(512), dim3(256), 0, stream,
                       xqn_h, xqn_l, xkvn_h, xkvn_l, ptn_h, ptn_l,
                       WqT_h, WqT_l, WkvT_h, WkvT_l, WcT_h, WcT_l,
                       bq, bkv, bc, Qb, KVb, Cb);
    hipLaunchKernelGGL(csum_kernel, dim3(128), dim3(256), 0, stream, Cb, csum);
    hipLaunchKernelGGL(scanp_kernel, dim3(128), dim3(256), 0, stream, Cb, csum, Pb);
    hipLaunchKernelGGL(abv_kernel, dim3(4352), dim3(256), 0, stream,
                       Qb, KVb, Pb, cw, Aah, Aal, Bah, Bal, VTb);
    hipLaunchKernelGGL(attn_kernel, dim3(1024), dim3(256), 0, stream,
                       Aah, Aal, Bah, Bal, VTb, wv_h, wv_l);
    hipLaunchKernelGGL(outgemm_kernel, dim3(512), dim3(128), 0, stream,
                       wv_h, wv_l, WoT_h, WoT_l, bout, out);
}